// Round 6
// baseline (113.795 us; speedup 1.0000x reference)
//
#include <hip/hip_runtime.h>

// EulerRNNCell — Genois qubit SDE Euler-Maruyama rollout.
// B=512, NUM_TRAJ=64, 255 steps.
//
// R6 theory: R3-R5 all mapped wave lanes to trajectories 1 MB apart (n =
// j*512+b) -> every wave-load touches 64 far-apart pages (TLB/translation
// serialization) which is why unroll/float4/prefetch were all neutral.
// Remap: lane j -> consecutive trajectory n = blockIdx*64+j, so a wave works
// in one contiguous 130 KB window. The 64-replica mean then crosses waves ->
// two kernels: (1) rollout writes xT as 3 SoA planes in d_ws (coalesced),
// (2) 512 threads reduce replicas (coalesced strided reads) + epilogue.
//
// Output layout (floats): [0,3584) = out[512,7]; rho real plane [3584,5632);
// imag plane [5632,7680) if room.

#define BATCH   512
#define NTRAJ   64
#define NTOT    (BATCH * NTRAJ)   // 32768
#define TSTEPS  255

__device__ __forceinline__ void sde_step(float& x1, float& x2, float& x3,
                                         float w1, float w2, float omega)
{
    const float HG = 0.55f;                    // 0.5 * GAMMA
    const float K  = 0.44497190922573976f;     // sqrt(GAMMA*ETA/2)
    const float SD = 0.0625f;                  // sqrt(DT) = 2^-4 (exact)
    const float DT = 0.00390625f;              // 2^-8

    const float d1 = w1 * SD;
    const float d2 = w2 * SD;

    const float ax = -HG * x1;
    const float ay = -omega * x3 - HG * x2;
    const float az = omega * x2;

    const float bx = K * (-x1 * x3 * d1 + x2 * d2);
    const float by = K * (-x2 * x3 * d1 - x1 * d2);
    const float bz = K * ((1.0f - x3 * x3) * d1);

    const float y1 = x1 + DT * ax + bx;
    const float y2 = x2 + DT * ay + by;
    const float y3 = x3 + DT * az + bz;
    x1 = y1; x2 = y2; x3 = y3;
}

__device__ __forceinline__ void sde_step2(float& x1, float& x2, float& x3,
                                          float4 w, float omega)
{
    sde_step(x1, x2, x3, w.x, w.y, omega);
    sde_step(x1, x2, x3, w.z, w.w, omega);
}

// Kernel 1: one thread per trajectory, lanes on CONSECUTIVE trajectories.
__global__ __launch_bounds__(64) void euler_rollout_kernel(
    const float* __restrict__ inputs,   // [512,1]
    const float* __restrict__ bloch0,   // [3]
    const float* __restrict__ wvec,     // [32768, 255, 2]
    float* __restrict__ xs)             // ws: 3 planes of [32768]
{
    const int n = blockIdx.x * 64 + threadIdx.x;   // trajectory id
    const int b = n & (BATCH - 1);                 // n = r*512 + b, 512 pow2

    const float omega = inputs[b] + 1e-8f;

    float x1 = bloch0[0];
    float x2 = bloch0[1];
    float x3 = bloch0[2];

    // row of 255 float2 pairs; byte offset n*2040 -> 16B aligned iff n even
    // (lane-alternating parity: peel/tail are exec-masked, 1 step each)
    const float2* __restrict__ wrow =
        reinterpret_cast<const float2*>(wvec) + (long long)n * TSTEPS;

    const int head = (n & 1);
    if (head) {
        const float2 wh = wrow[0];
        sde_step(x1, x2, x3, wh.x, wh.y, omega);
    }
    const float4* __restrict__ w4 =
        reinterpret_cast<const float4*>(wrow + head);

    // software pipeline: chunks of 4 float4 (8 steps), double-buffered A/B
    float4 a0, a1, a2, a3, c0, c1, c2, c3;
    a0 = w4[0]; a1 = w4[1]; a2 = w4[2]; a3 = w4[3];

    int k = 0;
#pragma unroll 1
    for (int it = 0; it < 15; ++it) {
        c0 = w4[k + 4]; c1 = w4[k + 5]; c2 = w4[k + 6]; c3 = w4[k + 7];
        sde_step2(x1, x2, x3, a0, omega);
        sde_step2(x1, x2, x3, a1, omega);
        sde_step2(x1, x2, x3, a2, omega);
        sde_step2(x1, x2, x3, a3, omega);
        a0 = w4[k + 8]; a1 = w4[k + 9]; a2 = w4[k + 10]; a3 = w4[k + 11];
        sde_step2(x1, x2, x3, c0, omega);
        sde_step2(x1, x2, x3, c1, omega);
        sde_step2(x1, x2, x3, c2, omega);
        sde_step2(x1, x2, x3, c3, omega);
        k += 8;
    }
    // k = 120: A holds float4 120..123; remainder 124..126
    sde_step2(x1, x2, x3, a0, omega);
    sde_step2(x1, x2, x3, a1, omega);
    sde_step2(x1, x2, x3, a2, omega);
    sde_step2(x1, x2, x3, a3, omega);
    c0 = w4[124]; c1 = w4[125]; c2 = w4[126];
    sde_step2(x1, x2, x3, c0, omega);
    sde_step2(x1, x2, x3, c1, omega);
    sde_step2(x1, x2, x3, c2, omega);
    if (!head) {
        const float2 wt = wrow[254];
        sde_step(x1, x2, x3, wt.x, wt.y, omega);
    }

    // SoA planes, coalesced (consecutive n per wave)
    xs[n]            = x1;
    xs[NTOT + n]     = x2;
    xs[2 * NTOT + n] = x3;
}

// Kernel 2: reduce 64 replicas per batch element + epilogue.
__global__ __launch_bounds__(64) void reduce_epilogue_kernel(
    const float* __restrict__ inputs,   // [512,1]
    const float* __restrict__ xs,       // ws: 3 planes of [32768]
    float* __restrict__ out,            // [out_size]
    int out_size)
{
    const int b = blockIdx.x * 64 + threadIdx.x;   // 8 blocks x 64 = 512

    float s1 = 0.0f, s2 = 0.0f, s3 = 0.0f;
#pragma unroll 8
    for (int r = 0; r < NTRAJ; ++r) {
        const int n = r * BATCH + b;               // lane-consecutive -> coalesced
        s1 += xs[n];
        s2 += xs[NTOT + n];
        s3 += xs[2 * NTOT + n];
    }

    const float inv = 1.0f / (float)NTRAJ;
    const float xm1 = s1 * inv;
    const float xm2 = s2 * inv;
    const float xm3 = s3 * inv;

    float px = 0.5f * (xm1 + 1.0f);
    float py = 0.5f * (xm2 + 1.0f);
    float pz = 0.5f * (xm3 + 1.0f);

    float p0 = fminf(fmaxf(px, 0.0f), 1.0f);
    float p1 = fminf(fmaxf(1.0f - px, 0.0f), 1.0f);
    float p2 = fminf(fmaxf(py, 0.0f), 1.0f);
    float p3 = fminf(fmaxf(1.0f - py, 0.0f), 1.0f);
    float p4 = fminf(fmaxf(pz, 0.0f), 1.0f);
    float p5 = fminf(fmaxf(1.0f - pz, 0.0f), 1.0f);

    float* o = out + (long long)b * 7;
    o[0] = p0; o[1] = p1; o[2] = p2; o[3] = p3; o[4] = p4; o[5] = p5;
    o[6] = inputs[b];

    // rho real parts: [(1+z)/2, x/2, x/2, (1-z)/2] at [3584, 5632)
    float* rre = out + BATCH * 7 + (long long)b * 4;
    rre[0] = (1.0f + xm3) * 0.5f;
    rre[1] = xm1 * 0.5f;
    rre[2] = xm1 * 0.5f;
    rre[3] = (1.0f - xm3) * 0.5f;

    // rho imag parts: [0, -y/2, y/2, 0] at [5632, 7680) if buffer has room
    if (out_size >= BATCH * 7 + BATCH * 8) {
        float* rim = out + BATCH * 7 + BATCH * 4 + (long long)b * 4;
        rim[0] = 0.0f;
        rim[1] = -xm2 * 0.5f;
        rim[2] = xm2 * 0.5f;
        rim[3] = 0.0f;
    }
}

extern "C" void kernel_launch(void* const* d_in, const int* in_sizes, int n_in,
                              void* d_out, int out_size, void* d_ws, size_t ws_size,
                              hipStream_t stream) {
    const float* inputs = (const float*)d_in[0];   // [512,1]
    const float* bloch0 = (const float*)d_in[1];   // [3]
    const float* wvec   = (const float*)d_in[2];   // [32768,255,2]
    float* out = (float*)d_out;
    float* xs  = (float*)d_ws;                     // 3*32768 floats = 393 KB

    euler_rollout_kernel<<<dim3(NTOT / 64), dim3(64), 0, stream>>>(
        inputs, bloch0, wvec, xs);
    reduce_epilogue_kernel<<<dim3(BATCH / 64), dim3(64), 0, stream>>>(
        inputs, xs, out, out_size);
}